// Round 18
// baseline (555.280 us; speedup 1.0000x reference)
//
#include <hip/hip_runtime.h>
#include <hip/hip_bf16.h>
#include <stdint.h>

#define N_NODES 6144
#define FDIM    128
#define EEDGES  16384
#define KTOP    32
#define KSEL    40     // 40th-largest tile-max: >=8-rank margin (~6e-3) vs bf16 noise (2e-4)
#define MAXNBR  64
#define MAXCAND 512
#define NTILES  96     // N_NODES/64
#define GRIDY   16
#define TPB     (NTILES/GRIDY)   // 6 tiles per block

typedef short bf16x8 __attribute__((ext_vector_type(8)));
typedef float f32x4  __attribute__((ext_vector_type(4)));

__device__ __forceinline__ float elu_f(float x){ return x > 0.f ? x : expm1f(x); }

__device__ __forceinline__ unsigned short f2bf(float f){
  unsigned int u = __float_as_uint(f);
  u += 0x7FFFu + ((u >> 16) & 1u);   // RNE
  return (unsigned short)(u >> 16);
}
__device__ __forceinline__ float bf2f(unsigned short h){
  return __uint_as_float(((unsigned int)h) << 16);
}

// ---------------------------------------------------------------- prep: adj_scan (blocks 0..6143) + xprep x2 rows (6144..9215)
__global__ __launch_bounds__(256) void prep(const float* __restrict__ adj,
    const float* __restrict__ x, int* __restrict__ nbr, int* __restrict__ nbrcnt,
    int* __restrict__ colcnt, unsigned short* __restrict__ xbf,
    float* __restrict__ xninv, float* __restrict__ cat1){
  const int b = blockIdx.x, t = threadIdx.x;
  if (b < N_NODES){                         // ---- adj_scan row
    const int i = b;
    __shared__ int s_cnt;
    if (t == 0) s_cnt = 0;
    __syncthreads();
    const float4* row = (const float4*)(adj + (size_t)i * N_NODES);
    for (int v = t; v < N_NODES/4; v += 256){
      float4 f = row[v];
      int c = v * 4;
      if (f.x != 0.f){ int s = atomicAdd(&s_cnt,1); if (s < MAXNBR) nbr[i*MAXNBR+s] = c;   atomicAdd(&colcnt[c],1); }
      if (f.y != 0.f){ int s = atomicAdd(&s_cnt,1); if (s < MAXNBR) nbr[i*MAXNBR+s] = c+1; atomicAdd(&colcnt[c+1],1); }
      if (f.z != 0.f){ int s = atomicAdd(&s_cnt,1); if (s < MAXNBR) nbr[i*MAXNBR+s] = c+2; atomicAdd(&colcnt[c+2],1); }
      if (f.w != 0.f){ int s = atomicAdd(&s_cnt,1); if (s < MAXNBR) nbr[i*MAXNBR+s] = c+3; atomicAdd(&colcnt[c+3],1); }
    }
    __syncthreads();
    if (t == 0) nbrcnt[i] = min(s_cnt, MAXNBR);
  } else {                                  // ---- xprep, 2 rows per block
    const int i = (b - N_NODES)*2 + (t >> 7);
    const int tl = t & 127;
    float v = x[(size_t)i*FDIM + tl];
    xbf[(size_t)i*FDIM + tl] = f2bf(v);
    cat1[(size_t)i*256 + tl] = v;           // folded copy128
    float s = v * v;
    for (int o = 32; o > 0; o >>= 1) s += __shfl_down(s, o, 64);
    __shared__ float ws[4];
    if ((t & 63) == 0) ws[t >> 6] = s;
    __syncthreads();
    if (tl == 0) xninv[i] = rsqrtf(ws[(t>>7)*2] + ws[(t>>7)*2 + 1]);
  }
}

// ---------------------------------------------------------------- LDS overlays for the fused simgemm+gemm_dual kernel
struct SimS {
  unsigned short Abf[64][136];
  unsigned short Bbf[64][136];
  unsigned short Stile[64][72];
  float nrow[64];
  float ncol[64];
  float wmax[4][64];
};
struct GemmS {
  float Alds[32][34];
  float B1lds[32][68];
  float B2lds[32][68];
};

// dual-GEMM body: T1 = x@Wg1, T2 = elu(x@Wp1 + b1), using overlay LDS
__device__ __forceinline__ void gemm_dual_body(GemmS& g, const float* __restrict__ A,
    const float* __restrict__ B1, const float* __restrict__ B2,
    const float* __restrict__ bias2, float* __restrict__ C1, float* __restrict__ C2,
    int R0, int C0){
  const int t = threadIdx.x;
  const int rg = t >> 4, cg = t & 15;
  float4 p0 = {0,0,0,0}, p1 = {0,0,0,0};
  float4 q0 = {0,0,0,0}, q1 = {0,0,0,0};
  for (int kc = 0; kc < FDIM; kc += 32){
    __syncthreads();
    { int r = t >> 3, k0 = (t & 7) * 4;
      float4 f = *(const float4*)(A + (size_t)(R0 + r)*FDIM + kc + k0);
      g.Alds[k0+0][r] = f.x; g.Alds[k0+1][r] = f.y; g.Alds[k0+2][r] = f.z; g.Alds[k0+3][r] = f.w; }
#pragma unroll
    for (int e = 0; e < 2; ++e){
      int idx = t + e*256;
      int k = idx >> 4, m4 = idx & 15;
      *(float4*)&g.B1lds[k][m4*4] = *(const float4*)(B1 + (size_t)(kc + k)*FDIM + C0 + m4*4);
      *(float4*)&g.B2lds[k][m4*4] = *(const float4*)(B2 + (size_t)(kc + k)*FDIM + C0 + m4*4);
    }
    __syncthreads();
#pragma unroll
    for (int k = 0; k < 32; ++k){
      float2 a = *(const float2*)&g.Alds[k][rg*2];
      float4 b = *(const float4*)&g.B1lds[k][cg*4];
      float4 c = *(const float4*)&g.B2lds[k][cg*4];
      p0.x += a.x*b.x; p0.y += a.x*b.y; p0.z += a.x*b.z; p0.w += a.x*b.w;
      p1.x += a.y*b.x; p1.y += a.y*b.y; p1.z += a.y*b.z; p1.w += a.y*b.w;
      q0.x += a.x*c.x; q0.y += a.x*c.y; q0.z += a.x*c.z; q0.w += a.x*c.w;
      q1.x += a.y*c.x; q1.y += a.y*c.y; q1.z += a.y*c.z; q1.w += a.y*c.w;
    }
  }
  const int r0 = R0 + rg*2, c0 = C0 + cg*4;
  *(float4*)&C1[(size_t)r0*FDIM + c0] = p0;
  *(float4*)&C1[(size_t)(r0+1)*FDIM + c0] = p1;
  float4 bb = *(const float4*)&bias2[c0];
  q0.x = elu_f(q0.x + bb.x); q0.y = elu_f(q0.y + bb.y); q0.z = elu_f(q0.z + bb.z); q0.w = elu_f(q0.w + bb.w);
  q1.x = elu_f(q1.x + bb.x); q1.y = elu_f(q1.y + bb.y); q1.z = elu_f(q1.z + bb.z); q1.w = elu_f(q1.w + bb.w);
  *(float4*)&C2[(size_t)r0*FDIM + c0] = q0;
  *(float4*)&C2[(size_t)(r0+1)*FDIM + c0] = q1;
}

// ---------------------------------------------------------------- simgemm_dual:
// [0,1536): bf16 cosine tiles (64 rows x 6 tiles/block) + per-tile row maxes
// [1536,1920): gemm_dual T1=x@Wg1, T2=elu(x@Wp1+b1) + node_norms fold
__global__ __launch_bounds__(256) void simgemm_dual(const unsigned short* __restrict__ xbf,
    const float* __restrict__ xninv, unsigned short* __restrict__ sim,
    float* __restrict__ gmax,
    const float* __restrict__ x, const float* __restrict__ Wg1,
    const float* __restrict__ Wp1, const float* __restrict__ b1,
    float* __restrict__ T1, float* __restrict__ T2,
    const int* __restrict__ nbrcnt, const int* __restrict__ colcnt,
    float* __restrict__ d1inv, float* __restrict__ d2inv){
  __shared__ union { SimS s; GemmS g; } sh;   // 44.5 KB (sim part dominates)
  const int t = threadIdx.x;

  if (blockIdx.x >= 1536){                  // ---- gemm_dual part
    const int bb = blockIdx.x - 1536;       // 384 blocks
    const int R0 = (bb % 192)*32, C0 = (bb / 192)*64;
    if (bb < 192 && t < 32){                // folded node_norms
      int i = R0 + t;
      d1inv[i] = rsqrtf((float)(nbrcnt[i] + 1));
      d2inv[i] = rsqrtf((float)(colcnt[i] + 1));
    }
    gemm_dual_body(sh.g, x, Wg1, Wp1, b1, T1, T2, R0, C0);
    return;
  }

  const int R0   = (blockIdx.x % 96) * 64;
  const int tb0  = (blockIdx.x / 96) * TPB;
  const int lane = t & 63, w = t >> 6;
  const int lr   = lane & 15, q8 = (lane >> 4) * 8, quad = lane >> 4;

  for (int e = t; e < 64*16; e += 256){
    int r = e >> 4, c8 = e & 15;
    *(uint4*)&sh.s.Abf[r][c8*8] = ((const uint4*)(xbf + (size_t)(R0 + r)*FDIM))[c8];
  }
  if (t < 64) sh.s.nrow[t] = xninv[R0 + t];

  for (int tb = tb0; tb < tb0 + TPB; ++tb){
    __syncthreads();
    for (int e = t; e < 64*16; e += 256){
      int r = e >> 4, c8 = e & 15;
      *(uint4*)&sh.s.Bbf[r][c8*8] = ((const uint4*)(xbf + (size_t)(tb*64 + r)*FDIM))[c8];
    }
    if (t < 64) sh.s.ncol[t] = xninv[tb*64 + t];
    __syncthreads();

    f32x4 acc[4] = {};
#pragma unroll
    for (int kb = 0; kb < 4; ++kb){
      bf16x8 bcol = *(const bf16x8*)&sh.s.Bbf[w*16 + lr][kb*32 + q8];
#pragma unroll
      for (int f = 0; f < 4; ++f){
        bf16x8 arow = *(const bf16x8*)&sh.s.Abf[f*16 + lr][kb*32 + q8];
        acc[f] = __builtin_amdgcn_mfma_f32_16x16x32_bf16(bcol, arow, acc[f], 0, 0, 0);
      }
    }
    const int scol0 = w*16 + quad*4;
    const float nc0 = sh.s.ncol[scol0], nc1 = sh.s.ncol[scol0+1],
                nc2 = sh.s.ncol[scol0+2], nc3 = sh.s.ncol[scol0+3];
#pragma unroll
    for (int f = 0; f < 4; ++f){
      const int srow = f*16 + lr;
      const float nr = sh.s.nrow[srow];
      const int grow = R0 + srow, gcol0 = tb*64 + scol0;
      float v0 = acc[f][0]*nr*nc0, v1 = acc[f][1]*nr*nc1,
            v2 = acc[f][2]*nr*nc2, v3 = acc[f][3]*nr*nc3;
      if (grow == gcol0    ) v0 = -2.0f;
      if (grow == gcol0 + 1) v1 = -2.0f;
      if (grow == gcol0 + 2) v2 = -2.0f;
      if (grow == gcol0 + 3) v3 = -2.0f;
      unsigned int h0 = f2bf(v0), h1 = f2bf(v1), h2 = f2bf(v2), h3 = f2bf(v3);
      uint2 p; p.x = h0 | (h1 << 16); p.y = h2 | (h3 << 16);
      *(uint2*)&sh.s.Stile[srow][scol0] = p;
      float rmax = fmaxf(fmaxf(bf2f(h0), bf2f(h1)), fmaxf(bf2f(h2), bf2f(h3)));
      rmax = fmaxf(rmax, __shfl_xor(rmax, 16, 64));
      rmax = fmaxf(rmax, __shfl_xor(rmax, 32, 64));
      if (quad == 0) sh.s.wmax[w][srow] = rmax;
    }
    __syncthreads();
#pragma unroll
    for (int e0 = 0; e0 < 2; ++e0){
      int e = t + e0*256;
      int r = e >> 3, c8 = e & 7;
      *(uint4*)&sim[(size_t)(R0 + r)*N_NODES + tb*64 + c8*8] = *(uint4*)&sh.s.Stile[r][c8*8];
    }
    if (t < 64){
      float g = fmaxf(fmaxf(sh.s.wmax[0][t], sh.s.wmax[1][t]),
                      fmaxf(sh.s.wmax[2][t], sh.s.wmax[3][t]));
      gmax[(size_t)(R0 + t)*NTILES + tb] = g;
    }
  }
}

// ---------------------------------------------------------------- refine_scan: inline tau + scan sim row + exact fp32 top-32
__global__ __launch_bounds__(256) void refine_scan(const float* __restrict__ x,
    const float* __restrict__ xninv, const unsigned short* __restrict__ sim,
    const float* __restrict__ gmax, float* __restrict__ tval, int* __restrict__ tidx,
    float* __restrict__ deginv){
  const int i = blockIdx.x, t = threadIdx.x;
  __shared__ float xi[128];
  __shared__ float gm[NTILES];
  __shared__ float tauv;
  __shared__ float cv[MAXCAND];
  __shared__ int   ci[MAXCAND];
  __shared__ float sel[KTOP];
  __shared__ int   cnt;
  if (t == 0) cnt = 0;
  if (t < 32) *(float4*)&xi[t*4] = *(const float4*)(x + (size_t)i*FDIM + t*4);
  if (t < NTILES) gm[t] = gmax[(size_t)i*NTILES + t];
  __syncthreads();
  if (t < NTILES){                          // rank-select KSEL-th-largest tile-max
    float v = gm[t]; int rank = 0;
    for (int j = 0; j < NTILES; ++j){
      float u = gm[j];
      if (u > v || (u == v && j < t)) rank++;
    }
    if (rank == KSEL-1) tauv = v;
  }
  __syncthreads();
  const float taui = tauv;
  const uint4* srow = (const uint4*)(sim + (size_t)i*N_NODES);
  for (int v8 = t; v8 < N_NODES/8; v8 += 256){
    uint4 u = srow[v8];
    const unsigned short* h = (const unsigned short*)&u;
#pragma unroll
    for (int q = 0; q < 8; ++q){
      if (bf2f(h[q]) >= taui){              // diag stored as -2 -> never passes
        int s = atomicAdd(&cnt, 1);
        if (s < MAXCAND) ci[s] = v8*8 + q;
      }
    }
  }
  __syncthreads();
  int n = cnt; if (n > MAXCAND) n = MAXCAND;
  const float ni = xninv[i];
  const int part = t & 1, cb = t >> 1;      // 2 lanes per candidate, 128/pass
  for (int c0 = 0; c0 < n; c0 += 128){
    const int c = c0 + cb;
    float acc = 0.f;
    int idx = 0;
    if (c < n){
      idx = ci[c];
      const float* xc = x + (size_t)idx*FDIM + part*64;
#pragma unroll
      for (int q = 0; q < 16; ++q){
        float4 f = *(const float4*)(xc + q*4);
        const float* a = &xi[part*64 + q*4];
        acc += a[0]*f.x + a[1]*f.y + a[2]*f.z + a[3]*f.w;
      }
    }
    acc += __shfl_xor(acc, 1, 64);
    if (c < n && part == 0) cv[c] = acc * ni * xninv[idx];
  }
  __syncthreads();
  for (int c = t; c < n; c += 256){
    float v = cv[c]; int id = ci[c];
    int rank = 0;
    for (int j = 0; j < n; ++j){
      float u = cv[j];
      if (u > v || (u == v && ci[j] < id)) rank++;   // top_k tie-break: lower index
    }
    if (rank < KTOP){
      tval[(size_t)i*KTOP + rank] = v;
      tidx[(size_t)i*KTOP + rank] = id;
      sel[rank] = v;
    }
  }
  __syncthreads();
  if (t == 0){
    float s = 0.f;
    for (int q = 0; q < KTOP; ++q) s += sel[q];
    deginv[i] = 1.0f / fmaxf(s, 1e-5f);
  }
}

// ---------------------------------------------------------------- generic 32x64 gemm body (B pitch = ldb), runtime K
__device__ __forceinline__ void gemm_body(const float* __restrict__ A, int lda,
    const float* __restrict__ B, int ldb, const float* __restrict__ bias,
    float* __restrict__ C, int ldc, int K, int act, int R0, int C0){
  const int t = threadIdx.x;
  const int rg = t >> 4, cg = t & 15;
  __shared__ float Alds[32][34];
  __shared__ float Blds[32][68];
  float4 acc0 = {0,0,0,0}, acc1 = {0,0,0,0};
  for (int kc = 0; kc < K; kc += 32){
    __syncthreads();
    { int r = t >> 3, k0 = (t & 7) * 4;
      float4 f = *(const float4*)(A + (size_t)(R0 + r)*lda + kc + k0);
      Alds[k0+0][r] = f.x; Alds[k0+1][r] = f.y; Alds[k0+2][r] = f.z; Alds[k0+3][r] = f.w; }
#pragma unroll
    for (int e = 0; e < 2; ++e){
      int idx = t + e*256;
      int k = idx >> 4, m4 = idx & 15;
      *(float4*)&Blds[k][m4*4] = *(const float4*)(B + (size_t)(kc + k)*ldb + C0 + m4*4);
    }
    __syncthreads();
#pragma unroll
    for (int k = 0; k < 32; ++k){
      float2 a = *(const float2*)&Alds[k][rg*2];
      float4 b = *(const float4*)&Blds[k][cg*4];
      acc0.x += a.x*b.x; acc0.y += a.x*b.y; acc0.z += a.x*b.z; acc0.w += a.x*b.w;
      acc1.x += a.y*b.x; acc1.y += a.y*b.y; acc1.z += a.y*b.z; acc1.w += a.y*b.w;
    }
  }
  const int r0 = R0 + rg*2, c0 = C0 + cg*4;
  float4 bb = {0,0,0,0};
  if (bias) bb = *(const float4*)&bias[c0];
  acc0.x += bb.x; acc0.y += bb.y; acc0.z += bb.z; acc0.w += bb.w;
  acc1.x += bb.x; acc1.y += bb.y; acc1.z += bb.z; acc1.w += bb.w;
  if (act){
    acc0.x = elu_f(acc0.x); acc0.y = elu_f(acc0.y); acc0.z = elu_f(acc0.z); acc0.w = elu_f(acc0.w);
    acc1.x = elu_f(acc1.x); acc1.y = elu_f(acc1.y); acc1.z = elu_f(acc1.z); acc1.w = elu_f(acc1.w);
  }
  *(float4*)&C[(size_t)r0*ldc + c0] = acc0;
  *(float4*)&C[(size_t)(r0+1)*ldc + c0] = acc1;
}

// ---------------------------------------------------------------- fp32 GEMM  C[N x M] = act(A@B + bias)  (B pitch = M)
template<int M>
__global__ __launch_bounds__(256) void gemm_k(const float* __restrict__ A, int lda,
    const float* __restrict__ B, const float* __restrict__ bias,
    float* __restrict__ C, int ldc, int K, int act){
  gemm_body(A, lda, B, M, bias, C, ldc, K, act, blockIdx.x*32, blockIdx.y*64);
}

// ---------------------------------------------------------------- spmm_pair: gcn layer-1 (blocks 0..6143) + sage layer-1 (6144..12287)
__global__ __launch_bounds__(128) void spmm_pair(const float* __restrict__ T1,
    const int* __restrict__ nbr, const int* __restrict__ nbrcnt,
    const float* __restrict__ d1inv, const float* __restrict__ d2inv,
    float* __restrict__ z1,
    const float* __restrict__ T2, const float* __restrict__ tval,
    const int* __restrict__ tidx, const float* __restrict__ deginv,
    float* __restrict__ cat1r){
  const int b = blockIdx.x, t = threadIdx.x;
  if (b < N_NODES){
    const int i = b;
    float acc = T1[(size_t)i*FDIM + t] * d2inv[i];
    const int cnt = nbrcnt[i];
    const int* nb = nbr + (size_t)i*MAXNBR;
    for (int s = 0; s < cnt; ++s){
      int j = nb[s];
      acc += T1[(size_t)j*FDIM + t] * d2inv[j];
    }
    z1[(size_t)i*FDIM + t] = elu_f(acc * d1inv[i]);
  } else {
    const int i = b - N_NODES;
    float acc = 0.f;
    const float* vv = tval + (size_t)i*KTOP;
    const int*   ii = tidx + (size_t)i*KTOP;
    for (int s = 0; s < KTOP; ++s)
      acc += vv[s] * T2[(size_t)ii[s]*FDIM + t];
    cat1r[(size_t)i*256 + t] = acc * deginv[i];
  }
}

// ---------------------------------------------------------------- dual_stage1: [0,384) T1 = z1@Wg2 ; [384,768) cat2[:,0:128] = elu(cat1@Ws1)
__global__ __launch_bounds__(256) void dual_stage1(const float* __restrict__ z1,
    const float* __restrict__ Wg2, float* __restrict__ T1,
    const float* __restrict__ cat1, const float* __restrict__ Ws1,
    float* __restrict__ cat2){
  const int b = blockIdx.x;
  if (b < 384){
    gemm_body(z1, FDIM, Wg2, FDIM, nullptr, T1, FDIM, FDIM, 0,
              (b % 192)*32, (b / 192)*64);
  } else {
    const int bb = b - 384;
    gemm_body(cat1, 256, Ws1, FDIM, nullptr, cat2, 256, 256, 1,
              (bb % 192)*32, (bb / 192)*64);
  }
}

// ---------------------------------------------------------------- dual_stage2: [0,3072) GCN-L2 spmm (2 rows/block) ; [3072,3456) T2 = elu(cat2@Wp2+b2)
__global__ __launch_bounds__(256) void dual_stage2(const float* __restrict__ T1,
    const int* __restrict__ nbr, const int* __restrict__ nbrcnt,
    const float* __restrict__ d1inv, const float* __restrict__ d2inv,
    float* __restrict__ hcat,
    const float* __restrict__ cat2, const float* __restrict__ Wp2,
    const float* __restrict__ b2, float* __restrict__ T2){
  const int b = blockIdx.x, t = threadIdx.x;
  if (b < 3072){
    const int i = b*2 + (t >> 7);
    const int tl = t & 127;
    float acc = T1[(size_t)i*FDIM + tl] * d2inv[i];
    const int cnt = nbrcnt[i];
    const int* nb = nbr + (size_t)i*MAXNBR;
    for (int s = 0; s < cnt; ++s){
      int j = nb[s];
      acc += T1[(size_t)j*FDIM + tl] * d2inv[j];
    }
    hcat[(size_t)i*256 + tl] = elu_f(acc * d1inv[i]);
  } else {
    const int bb = b - 3072;
    gemm_body(cat2, 256, Wp2, FDIM, b2, T2, FDIM, FDIM, 1,
              (bb % 192)*32, (bb / 192)*64);
  }
}

// ---------------------------------------------------------------- SAGE SpMM
__global__ __launch_bounds__(128) void spmm_sage(const float* __restrict__ P,
    const float* __restrict__ tval, const int* __restrict__ tidx,
    const float* __restrict__ deginv, float* __restrict__ C, int ldc){
  const int i = blockIdx.x, t = threadIdx.x;
  float acc = 0.f;
  const float* vv = tval + (size_t)i*KTOP;
  const int*   ii = tidx + (size_t)i*KTOP;
  for (int s = 0; s < KTOP; ++s)
    acc += vv[s] * P[(size_t)ii[s]*FDIM + t];
  C[(size_t)i*ldc + t] = acc * deginv[i];
}

// ---------------------------------------------------------------- edges: logits + per-block partial BCE (no global atomics)
__global__ __launch_bounds__(256) void edge_loss(const int* __restrict__ src,
    const int* __restrict__ dst, const float* __restrict__ labels,
    const float* __restrict__ HP, const float* __restrict__ hcat,
    const float* __restrict__ predB, float* __restrict__ out,
    float* __restrict__ partial){
  const int t = threadIdx.x;
  const int e = blockIdx.x*4 + (t >> 6);
  const int lane = t & 63;
  const int s = src[e], d = dst[e];
  const float* hp = HP   + (size_t)s*256;
  const float* hc = hcat + (size_t)d*256;
  float acc = 0.f;
  for (int k = lane; k < 256; k += 64) acc += hp[k] * hc[k];
  for (int o = 32; o > 0; o >>= 1) acc += __shfl_down(acc, o, 64);
  __shared__ float terms[4];
  if (lane == 0){
    float l = acc + predB[0];
    out[1 + e] = l;
    float y = labels[e];
    terms[t >> 6] = fmaxf(l, 0.f) - l*y + log1pf(expf(-fabsf(l)));
  }
  __syncthreads();
  if (t == 0) partial[blockIdx.x] = terms[0] + terms[1] + terms[2] + terms[3];
}

__global__ __launch_bounds__(256) void reduce_loss(const float* __restrict__ partial,
    float* __restrict__ out){
  const int t = threadIdx.x, lane = t & 63, w = t >> 6;
  float s = 0.f;
  for (int i = t; i < EEDGES/4; i += 256) s += partial[i];
  for (int o = 32; o > 0; o >>= 1) s += __shfl_down(s, o, 64);
  __shared__ float ws[4];
  if (lane == 0) ws[w] = s;
  __syncthreads();
  if (t == 0) out[0] = (ws[0] + ws[1] + ws[2] + ws[3]) * (1.0f / EEDGES);
}

// ---------------------------------------------------------------- launcher
extern "C" void kernel_launch(void* const* d_in, const int* in_sizes, int n_in,
                              void* d_out, int out_size, void* d_ws, size_t ws_size,
                              hipStream_t stream){
  (void)in_sizes; (void)n_in; (void)out_size; (void)ws_size;
  const int*   src    = (const int*)d_in[0];
  const int*   dst    = (const int*)d_in[1];
  const float* labels = (const float*)d_in[2];
  const float* adj    = (const float*)d_in[3];
  const float* x      = (const float*)d_in[4];
  const float* Wg1    = (const float*)d_in[5];
  const float* Wg2    = (const float*)d_in[6];
  const float* Wp1    = (const float*)d_in[7];
  const float* b1     = (const float*)d_in[8];
  const float* Ws1    = (const float*)d_in[9];
  const float* Wp2    = (const float*)d_in[10];
  const float* b2     = (const float*)d_in[11];
  const float* Ws2    = (const float*)d_in[12];
  const float* PredW  = (const float*)d_in[13];
  const float* PredB  = (const float*)d_in[14];

  char* ws = (char*)d_ws;
  size_t off = 0;
  auto alloc = [&](size_t bytes)->void*{
    void* p = ws + off; off += (bytes + 255) & ~(size_t)255; return p; };

  // total ws footprint ~109 MB (ws_size = 576 MiB)
  int*   colcnt = (int*)  alloc((size_t)N_NODES*4);
  int*   nbrcnt = (int*)  alloc((size_t)N_NODES*4);
  int*   nbr    = (int*)  alloc((size_t)N_NODES*MAXNBR*4);
  float* d1inv  = (float*)alloc((size_t)N_NODES*4);
  float* d2inv  = (float*)alloc((size_t)N_NODES*4);
  float* xninv  = (float*)alloc((size_t)N_NODES*4);
  unsigned short* xbf = (unsigned short*)alloc((size_t)N_NODES*FDIM*2);
  float* tval   = (float*)alloc((size_t)N_NODES*KTOP*4);
  int*   tidx   = (int*)  alloc((size_t)N_NODES*KTOP*4);
  float* dginv  = (float*)alloc((size_t)N_NODES*4);
  float* gmax   = (float*)alloc((size_t)N_NODES*NTILES*4);
  float* partial= (float*)alloc((size_t)(EEDGES/4)*4);
  float* T1     = (float*)alloc((size_t)N_NODES*FDIM*4);
  float* T2     = (float*)alloc((size_t)N_NODES*FDIM*4);
  float* z1     = (float*)alloc((size_t)N_NODES*FDIM*4);
  float* cat1   = (float*)alloc((size_t)N_NODES*256*4);
  float* cat2   = (float*)alloc((size_t)N_NODES*256*4);
  float* hcat   = (float*)alloc((size_t)N_NODES*256*4);
  unsigned short* sim = (unsigned short*)alloc((size_t)N_NODES*N_NODES*2);
  float* out    = (float*)d_out;

  hipMemsetAsync(colcnt, 0, (size_t)N_NODES*4, stream);

  prep        <<<N_NODES + N_NODES/2, 256, 0, stream>>>(adj, x, nbr, nbrcnt, colcnt, xbf, xninv, cat1);
  // sim tiles + gmax (1536 blocks) || T1=x@Wg1, T2=elu(x@Wp1+b1) + node_norms (384 blocks)
  simgemm_dual<<<1536 + 384, 256, 0, stream>>>(xbf, xninv, sim, gmax,
                                               x, Wg1, Wp1, b1, T1, T2,
                                               nbrcnt, colcnt, d1inv, d2inv);
  refine_scan <<<N_NODES, 256, 0, stream>>>(x, xninv, sim, gmax, tval, tidx, dginv);

  // GCN layer-1 spmm + SAGE layer-1 spmm
  spmm_pair   <<<2*N_NODES, 128, 0, stream>>>(T1, nbr, nbrcnt, d1inv, d2inv, z1,
                                              T2, tval, tidx, dginv, cat1 + 128);
  // T1 = z1@Wg2  ||  cat2[:,0:128] = elu(cat1@Ws1)
  dual_stage1 <<<768, 256, 0, stream>>>(z1, Wg2, T1, cat1, Ws1, cat2);
  // hcat[:,0:128] = GCN-L2 spmm(T1)  ||  T2 = elu(cat2@Wp2+b2)
  dual_stage2 <<<3072 + 384, 256, 0, stream>>>(T1, nbr, nbrcnt, d1inv, d2inv, hcat,
                                               cat2, Wp2, b2, T2);
  // SAGE layer-2 spmm + combine
  spmm_sage   <<<N_NODES, 128, 0, stream>>>(T2, tval, tidx, dginv, cat2 + 128, 256);
  gemm_k<128> <<<dim3(N_NODES/32, 2), 256, 0, stream>>>(cat2, 256, Ws2, nullptr, hcat + 128, 256, 256, 1);

  // predictor
  gemm_k<256> <<<dim3(N_NODES/32, 4), 256, 0, stream>>>(hcat, 256, PredW, nullptr, cat1, 256, 256, 0);
  edge_loss   <<<EEDGES/4, 256, 0, stream>>>(src, dst, labels, cat1, hcat, PredB, out, partial);
  reduce_loss <<<1, 256, 0, stream>>>(partial, out);
}

// Round 19
// 469.088 us; speedup vs baseline: 1.1837x; 1.1837x over previous
//
#include <hip/hip_runtime.h>
#include <hip/hip_bf16.h>
#include <stdint.h>

#define N_NODES 6144
#define FDIM    128
#define EEDGES  16384
#define KTOP    32
#define KSEL    40     // 40th-largest tile-max: >=8-rank margin (~6e-3) vs bf16 noise (2e-4)
#define MAXNBR  64
#define MAXCAND 512
#define NTILES  96     // N_NODES/64
#define GRIDY   16
#define TPB     (NTILES/GRIDY)   // 6 tiles per block

typedef short bf16x8 __attribute__((ext_vector_type(8)));
typedef float f32x4  __attribute__((ext_vector_type(4)));

__device__ __forceinline__ float elu_f(float x){ return x > 0.f ? x : expm1f(x); }

__device__ __forceinline__ unsigned short f2bf(float f){
  unsigned int u = __float_as_uint(f);
  u += 0x7FFFu + ((u >> 16) & 1u);   // RNE
  return (unsigned short)(u >> 16);
}
__device__ __forceinline__ float bf2f(unsigned short h){
  return __uint_as_float(((unsigned int)h) << 16);
}

// ---------------------------------------------------------------- prep: adj_scan (blocks 0..6143) + xprep x2 rows (6144..9215)
__global__ __launch_bounds__(256) void prep(const float* __restrict__ adj,
    const float* __restrict__ x, int* __restrict__ nbr, int* __restrict__ nbrcnt,
    int* __restrict__ colcnt, unsigned short* __restrict__ xbf,
    float* __restrict__ xninv, float* __restrict__ cat1){
  const int b = blockIdx.x, t = threadIdx.x;
  if (b < N_NODES){                         // ---- adj_scan row
    const int i = b;
    __shared__ int s_cnt;
    if (t == 0) s_cnt = 0;
    __syncthreads();
    const float4* row = (const float4*)(adj + (size_t)i * N_NODES);
    for (int v = t; v < N_NODES/4; v += 256){
      float4 f = row[v];
      int c = v * 4;
      if (f.x != 0.f){ int s = atomicAdd(&s_cnt,1); if (s < MAXNBR) nbr[i*MAXNBR+s] = c;   atomicAdd(&colcnt[c],1); }
      if (f.y != 0.f){ int s = atomicAdd(&s_cnt,1); if (s < MAXNBR) nbr[i*MAXNBR+s] = c+1; atomicAdd(&colcnt[c+1],1); }
      if (f.z != 0.f){ int s = atomicAdd(&s_cnt,1); if (s < MAXNBR) nbr[i*MAXNBR+s] = c+2; atomicAdd(&colcnt[c+2],1); }
      if (f.w != 0.f){ int s = atomicAdd(&s_cnt,1); if (s < MAXNBR) nbr[i*MAXNBR+s] = c+3; atomicAdd(&colcnt[c+3],1); }
    }
    __syncthreads();
    if (t == 0) nbrcnt[i] = min(s_cnt, MAXNBR);
  } else {                                  // ---- xprep, 2 rows per block
    const int i = (b - N_NODES)*2 + (t >> 7);
    const int tl = t & 127;
    float v = x[(size_t)i*FDIM + tl];
    xbf[(size_t)i*FDIM + tl] = f2bf(v);
    cat1[(size_t)i*256 + tl] = v;           // folded copy128
    float s = v * v;
    for (int o = 32; o > 0; o >>= 1) s += __shfl_down(s, o, 64);
    __shared__ float ws[4];
    if ((t & 63) == 0) ws[t >> 6] = s;
    __syncthreads();
    if (tl == 0) xninv[i] = rsqrtf(ws[(t>>7)*2] + ws[(t>>7)*2 + 1]);
  }
}

// ---------------------------------------------------------------- simgemm: bf16 cosine tiles + per-tile row maxes
// 64 rows x 6 tiles of 64 cols per block, grid (96,16). Operand-swapped MFMA.
__global__ __launch_bounds__(256) void simgemm(const unsigned short* __restrict__ xbf,
    const float* __restrict__ xninv, unsigned short* __restrict__ sim,
    float* __restrict__ gmax){
  const int t    = threadIdx.x;
  const int R0   = blockIdx.x * 64;
  const int tb0  = blockIdx.y * TPB;
  const int lane = t & 63, w = t >> 6;
  const int lr   = lane & 15, q8 = (lane >> 4) * 8, quad = lane >> 4;

  __shared__ unsigned short Abf[64][136];
  __shared__ unsigned short Bbf[64][136];
  __shared__ unsigned short Stile[64][72];
  __shared__ float nrow[64];
  __shared__ float ncol[64];
  __shared__ float wmax[4][64];

  for (int e = t; e < 64*16; e += 256){
    int r = e >> 4, c8 = e & 15;
    *(uint4*)&Abf[r][c8*8] = ((const uint4*)(xbf + (size_t)(R0 + r)*FDIM))[c8];
  }
  if (t < 64) nrow[t] = xninv[R0 + t];

  for (int tb = tb0; tb < tb0 + TPB; ++tb){
    __syncthreads();
    for (int e = t; e < 64*16; e += 256){
      int r = e >> 4, c8 = e & 15;
      *(uint4*)&Bbf[r][c8*8] = ((const uint4*)(xbf + (size_t)(tb*64 + r)*FDIM))[c8];
    }
    if (t < 64) ncol[t] = xninv[tb*64 + t];
    __syncthreads();

    f32x4 acc[4] = {};
#pragma unroll
    for (int kb = 0; kb < 4; ++kb){
      bf16x8 bcol = *(const bf16x8*)&Bbf[w*16 + lr][kb*32 + q8];
#pragma unroll
      for (int f = 0; f < 4; ++f){
        bf16x8 arow = *(const bf16x8*)&Abf[f*16 + lr][kb*32 + q8];
        acc[f] = __builtin_amdgcn_mfma_f32_16x16x32_bf16(bcol, arow, acc[f], 0, 0, 0);
      }
    }
    const int scol0 = w*16 + quad*4;
    const float nc0 = ncol[scol0], nc1 = ncol[scol0+1],
                nc2 = ncol[scol0+2], nc3 = ncol[scol0+3];
#pragma unroll
    for (int f = 0; f < 4; ++f){
      const int srow = f*16 + lr;
      const float nr = nrow[srow];
      const int grow = R0 + srow, gcol0 = tb*64 + scol0;
      float v0 = acc[f][0]*nr*nc0, v1 = acc[f][1]*nr*nc1,
            v2 = acc[f][2]*nr*nc2, v3 = acc[f][3]*nr*nc3;
      if (grow == gcol0    ) v0 = -2.0f;
      if (grow == gcol0 + 1) v1 = -2.0f;
      if (grow == gcol0 + 2) v2 = -2.0f;
      if (grow == gcol0 + 3) v3 = -2.0f;
      unsigned int h0 = f2bf(v0), h1 = f2bf(v1), h2 = f2bf(v2), h3 = f2bf(v3);
      uint2 p; p.x = h0 | (h1 << 16); p.y = h2 | (h3 << 16);
      *(uint2*)&Stile[srow][scol0] = p;
      float rmax = fmaxf(fmaxf(bf2f(h0), bf2f(h1)), fmaxf(bf2f(h2), bf2f(h3)));
      rmax = fmaxf(rmax, __shfl_xor(rmax, 16, 64));
      rmax = fmaxf(rmax, __shfl_xor(rmax, 32, 64));
      if (quad == 0) wmax[w][srow] = rmax;
    }
    __syncthreads();
#pragma unroll
    for (int e0 = 0; e0 < 2; ++e0){
      int e = t + e0*256;
      int r = e >> 3, c8 = e & 7;
      *(uint4*)&sim[(size_t)(R0 + r)*N_NODES + tb*64 + c8*8] = *(uint4*)&Stile[r][c8*8];
    }
    if (t < 64){
      float g = fmaxf(fmaxf(wmax[0][t], wmax[1][t]), fmaxf(wmax[2][t], wmax[3][t]));
      gmax[(size_t)(R0 + t)*NTILES + tb] = g;
    }
  }
}

// ---------------------------------------------------------------- refine_scan: inline tau + scan sim row + exact fp32 top-32
__global__ __launch_bounds__(256) void refine_scan(const float* __restrict__ x,
    const float* __restrict__ xninv, const unsigned short* __restrict__ sim,
    const float* __restrict__ gmax, float* __restrict__ tval, int* __restrict__ tidx,
    float* __restrict__ deginv){
  const int i = blockIdx.x, t = threadIdx.x;
  __shared__ float xi[128];
  __shared__ float gm[NTILES];
  __shared__ float tauv;
  __shared__ float cv[MAXCAND];
  __shared__ int   ci[MAXCAND];
  __shared__ float sel[KTOP];
  __shared__ int   cnt;
  if (t == 0) cnt = 0;
  if (t < 32) *(float4*)&xi[t*4] = *(const float4*)(x + (size_t)i*FDIM + t*4);
  if (t < NTILES) gm[t] = gmax[(size_t)i*NTILES + t];
  __syncthreads();
  if (t < NTILES){                          // rank-select KSEL-th-largest tile-max
    float v = gm[t]; int rank = 0;
    for (int j = 0; j < NTILES; ++j){
      float u = gm[j];
      if (u > v || (u == v && j < t)) rank++;
    }
    if (rank == KSEL-1) tauv = v;
  }
  __syncthreads();
  const float taui = tauv;
  const uint4* srow = (const uint4*)(sim + (size_t)i*N_NODES);
  for (int v8 = t; v8 < N_NODES/8; v8 += 256){
    uint4 u = srow[v8];
    const unsigned short* h = (const unsigned short*)&u;
#pragma unroll
    for (int q = 0; q < 8; ++q){
      if (bf2f(h[q]) >= taui){              // diag stored as -2 -> never passes
        int s = atomicAdd(&cnt, 1);
        if (s < MAXCAND) ci[s] = v8*8 + q;
      }
    }
  }
  __syncthreads();
  int n = cnt; if (n > MAXCAND) n = MAXCAND;
  const float ni = xninv[i];
  const int part = t & 1, cb = t >> 1;      // 2 lanes per candidate, 128/pass
  for (int c0 = 0; c0 < n; c0 += 128){
    const int c = c0 + cb;
    float acc = 0.f;
    int idx = 0;
    if (c < n){
      idx = ci[c];
      const float* xc = x + (size_t)idx*FDIM + part*64;
#pragma unroll
      for (int q = 0; q < 16; ++q){
        float4 f = *(const float4*)(xc + q*4);
        const float* a = &xi[part*64 + q*4];
        acc += a[0]*f.x + a[1]*f.y + a[2]*f.z + a[3]*f.w;
      }
    }
    acc += __shfl_xor(acc, 1, 64);
    if (c < n && part == 0) cv[c] = acc * ni * xninv[idx];
  }
  __syncthreads();
  for (int c = t; c < n; c += 256){
    float v = cv[c]; int id = ci[c];
    int rank = 0;
    for (int j = 0; j < n; ++j){
      float u = cv[j];
      if (u > v || (u == v && ci[j] < id)) rank++;   // top_k tie-break: lower index
    }
    if (rank < KTOP){
      tval[(size_t)i*KTOP + rank] = v;
      tidx[(size_t)i*KTOP + rank] = id;
      sel[rank] = v;
    }
  }
  __syncthreads();
  if (t == 0){
    float s = 0.f;
    for (int q = 0; q < KTOP; ++q) s += sel[q];
    deginv[i] = 1.0f / fmaxf(s, 1e-5f);
  }
}

// ---------------------------------------------------------------- generic 32x64 gemm body (B pitch = ldb), runtime K
__device__ __forceinline__ void gemm_body(const float* __restrict__ A, int lda,
    const float* __restrict__ B, int ldb, const float* __restrict__ bias,
    float* __restrict__ C, int ldc, int K, int act, int R0, int C0){
  const int t = threadIdx.x;
  const int rg = t >> 4, cg = t & 15;
  __shared__ float Alds[32][34];
  __shared__ float Blds[32][68];
  float4 acc0 = {0,0,0,0}, acc1 = {0,0,0,0};
  for (int kc = 0; kc < K; kc += 32){
    __syncthreads();
    { int r = t >> 3, k0 = (t & 7) * 4;
      float4 f = *(const float4*)(A + (size_t)(R0 + r)*lda + kc + k0);
      Alds[k0+0][r] = f.x; Alds[k0+1][r] = f.y; Alds[k0+2][r] = f.z; Alds[k0+3][r] = f.w; }
#pragma unroll
    for (int e = 0; e < 2; ++e){
      int idx = t + e*256;
      int k = idx >> 4, m4 = idx & 15;
      *(float4*)&Blds[k][m4*4] = *(const float4*)(B + (size_t)(kc + k)*ldb + C0 + m4*4);
    }
    __syncthreads();
#pragma unroll
    for (int k = 0; k < 32; ++k){
      float2 a = *(const float2*)&Alds[k][rg*2];
      float4 b = *(const float4*)&Blds[k][cg*4];
      acc0.x += a.x*b.x; acc0.y += a.x*b.y; acc0.z += a.x*b.z; acc0.w += a.x*b.w;
      acc1.x += a.y*b.x; acc1.y += a.y*b.y; acc1.z += a.y*b.z; acc1.w += a.y*b.w;
    }
  }
  const int r0 = R0 + rg*2, c0 = C0 + cg*4;
  float4 bb = {0,0,0,0};
  if (bias) bb = *(const float4*)&bias[c0];
  acc0.x += bb.x; acc0.y += bb.y; acc0.z += bb.z; acc0.w += bb.w;
  acc1.x += bb.x; acc1.y += bb.y; acc1.z += bb.z; acc1.w += bb.w;
  if (act){
    acc0.x = elu_f(acc0.x); acc0.y = elu_f(acc0.y); acc0.z = elu_f(acc0.z); acc0.w = elu_f(acc0.w);
    acc1.x = elu_f(acc1.x); acc1.y = elu_f(acc1.y); acc1.z = elu_f(acc1.z); acc1.w = elu_f(acc1.w);
  }
  *(float4*)&C[(size_t)r0*ldc + c0] = acc0;
  *(float4*)&C[(size_t)(r0+1)*ldc + c0] = acc1;
}

// ---------------------------------------------------------------- dual GEMM: T1 = x@Wg1, T2 = elu(x@Wp1 + b1); + node_norms fold
__global__ __launch_bounds__(256) void gemm_dual(const float* __restrict__ A,
    const float* __restrict__ B1, const float* __restrict__ B2,
    const float* __restrict__ bias2, float* __restrict__ C1, float* __restrict__ C2,
    const int* __restrict__ nbrcnt, const int* __restrict__ colcnt,
    float* __restrict__ d1inv, float* __restrict__ d2inv){
  const int t = threadIdx.x;
  const int R0 = blockIdx.x * 32, C0 = blockIdx.y * 64;
  if (blockIdx.y == 0 && t < 32){           // folded node_norms
    int i = R0 + t;
    d1inv[i] = rsqrtf((float)(nbrcnt[i] + 1));
    d2inv[i] = rsqrtf((float)(colcnt[i] + 1));
  }
  const int rg = t >> 4, cg = t & 15;
  __shared__ float Alds[32][34];
  __shared__ float B1lds[32][68];
  __shared__ float B2lds[32][68];
  float4 p0 = {0,0,0,0}, p1 = {0,0,0,0};
  float4 q0 = {0,0,0,0}, q1 = {0,0,0,0};
  for (int kc = 0; kc < FDIM; kc += 32){
    __syncthreads();
    { int r = t >> 3, k0 = (t & 7) * 4;
      float4 f = *(const float4*)(A + (size_t)(R0 + r)*FDIM + kc + k0);
      Alds[k0+0][r] = f.x; Alds[k0+1][r] = f.y; Alds[k0+2][r] = f.z; Alds[k0+3][r] = f.w; }
#pragma unroll
    for (int e = 0; e < 2; ++e){
      int idx = t + e*256;
      int k = idx >> 4, m4 = idx & 15;
      *(float4*)&B1lds[k][m4*4] = *(const float4*)(B1 + (size_t)(kc + k)*FDIM + C0 + m4*4);
      *(float4*)&B2lds[k][m4*4] = *(const float4*)(B2 + (size_t)(kc + k)*FDIM + C0 + m4*4);
    }
    __syncthreads();
#pragma unroll
    for (int k = 0; k < 32; ++k){
      float2 a = *(const float2*)&Alds[k][rg*2];
      float4 b = *(const float4*)&B1lds[k][cg*4];
      float4 c = *(const float4*)&B2lds[k][cg*4];
      p0.x += a.x*b.x; p0.y += a.x*b.y; p0.z += a.x*b.z; p0.w += a.x*b.w;
      p1.x += a.y*b.x; p1.y += a.y*b.y; p1.z += a.y*b.z; p1.w += a.y*b.w;
      q0.x += a.x*c.x; q0.y += a.x*c.y; q0.z += a.x*c.z; q0.w += a.x*c.w;
      q1.x += a.y*c.x; q1.y += a.y*c.y; q1.z += a.y*c.z; q1.w += a.y*c.w;
    }
  }
  const int r0 = R0 + rg*2, c0 = C0 + cg*4;
  *(float4*)&C1[(size_t)r0*FDIM + c0] = p0;
  *(float4*)&C1[(size_t)(r0+1)*FDIM + c0] = p1;
  float4 bb = *(const float4*)&bias2[c0];
  q0.x = elu_f(q0.x + bb.x); q0.y = elu_f(q0.y + bb.y); q0.z = elu_f(q0.z + bb.z); q0.w = elu_f(q0.w + bb.w);
  q1.x = elu_f(q1.x + bb.x); q1.y = elu_f(q1.y + bb.y); q1.z = elu_f(q1.z + bb.z); q1.w = elu_f(q1.w + bb.w);
  *(float4*)&C2[(size_t)r0*FDIM + c0] = q0;
  *(float4*)&C2[(size_t)(r0+1)*FDIM + c0] = q1;
}

// ---------------------------------------------------------------- fp32 GEMM  C[N x M] = act(A@B + bias)  (B pitch = M)
template<int M>
__global__ __launch_bounds__(256) void gemm_k(const float* __restrict__ A, int lda,
    const float* __restrict__ B, const float* __restrict__ bias,
    float* __restrict__ C, int ldc, int K, int act){
  gemm_body(A, lda, B, M, bias, C, ldc, K, act, blockIdx.x*32, blockIdx.y*64);
}

// ---------------------------------------------------------------- spmm_pair: gcn layer-1 (blocks 0..6143) + sage layer-1 (6144..12287)
__global__ __launch_bounds__(128) void spmm_pair(const float* __restrict__ T1,
    const int* __restrict__ nbr, const int* __restrict__ nbrcnt,
    const float* __restrict__ d1inv, const float* __restrict__ d2inv,
    float* __restrict__ z1,
    const float* __restrict__ T2, const float* __restrict__ tval,
    const int* __restrict__ tidx, const float* __restrict__ deginv,
    float* __restrict__ cat1r){
  const int b = blockIdx.x, t = threadIdx.x;
  if (b < N_NODES){
    const int i = b;
    float acc = T1[(size_t)i*FDIM + t] * d2inv[i];
    const int cnt = nbrcnt[i];
    const int* nb = nbr + (size_t)i*MAXNBR;
    for (int s = 0; s < cnt; ++s){
      int j = nb[s];
      acc += T1[(size_t)j*FDIM + t] * d2inv[j];
    }
    z1[(size_t)i*FDIM + t] = elu_f(acc * d1inv[i]);
  } else {
    const int i = b - N_NODES;
    float acc = 0.f;
    const float* vv = tval + (size_t)i*KTOP;
    const int*   ii = tidx + (size_t)i*KTOP;
    for (int s = 0; s < KTOP; ++s)
      acc += vv[s] * T2[(size_t)ii[s]*FDIM + t];
    cat1r[(size_t)i*256 + t] = acc * deginv[i];
  }
}

// ---------------------------------------------------------------- dual_stage1: [0,384) T1 = z1@Wg2 ; [384,768) cat2[:,0:128] = elu(cat1@Ws1)
__global__ __launch_bounds__(256) void dual_stage1(const float* __restrict__ z1,
    const float* __restrict__ Wg2, float* __restrict__ T1,
    const float* __restrict__ cat1, const float* __restrict__ Ws1,
    float* __restrict__ cat2){
  const int b = blockIdx.x;
  if (b < 384){
    gemm_body(z1, FDIM, Wg2, FDIM, nullptr, T1, FDIM, FDIM, 0,
              (b % 192)*32, (b / 192)*64);
  } else {
    const int bb = b - 384;
    gemm_body(cat1, 256, Ws1, FDIM, nullptr, cat2, 256, 256, 1,
              (bb % 192)*32, (bb / 192)*64);
  }
}

// ---------------------------------------------------------------- dual_stage2: [0,3072) GCN-L2 spmm (2 rows/block) ; [3072,3456) T2 = elu(cat2@Wp2+b2)
__global__ __launch_bounds__(256) void dual_stage2(const float* __restrict__ T1,
    const int* __restrict__ nbr, const int* __restrict__ nbrcnt,
    const float* __restrict__ d1inv, const float* __restrict__ d2inv,
    float* __restrict__ hcat,
    const float* __restrict__ cat2, const float* __restrict__ Wp2,
    const float* __restrict__ b2, float* __restrict__ T2){
  const int b = blockIdx.x, t = threadIdx.x;
  if (b < 3072){
    const int i = b*2 + (t >> 7);
    const int tl = t & 127;
    float acc = T1[(size_t)i*FDIM + tl] * d2inv[i];
    const int cnt = nbrcnt[i];
    const int* nb = nbr + (size_t)i*MAXNBR;
    for (int s = 0; s < cnt; ++s){
      int j = nb[s];
      acc += T1[(size_t)j*FDIM + tl] * d2inv[j];
    }
    hcat[(size_t)i*256 + tl] = elu_f(acc * d1inv[i]);
  } else {
    const int bb = b - 3072;
    gemm_body(cat2, 256, Wp2, FDIM, b2, T2, FDIM, FDIM, 1,
              (bb % 192)*32, (bb / 192)*64);
  }
}

// ---------------------------------------------------------------- SAGE SpMM
__global__ __launch_bounds__(128) void spmm_sage(const float* __restrict__ P,
    const float* __restrict__ tval, const int* __restrict__ tidx,
    const float* __restrict__ deginv, float* __restrict__ C, int ldc){
  const int i = blockIdx.x, t = threadIdx.x;
  float acc = 0.f;
  const float* vv = tval + (size_t)i*KTOP;
  const int*   ii = tidx + (size_t)i*KTOP;
  for (int s = 0; s < KTOP; ++s)
    acc += vv[s] * P[(size_t)ii[s]*FDIM + t];
  C[(size_t)i*ldc + t] = acc * deginv[i];
}

// ---------------------------------------------------------------- edges: logits + per-block partial BCE (no global atomics)
__global__ __launch_bounds__(256) void edge_loss(const int* __restrict__ src,
    const int* __restrict__ dst, const float* __restrict__ labels,
    const float* __restrict__ HP, const float* __restrict__ hcat,
    const float* __restrict__ predB, float* __restrict__ out,
    float* __restrict__ partial){
  const int t = threadIdx.x;
  const int e = blockIdx.x*4 + (t >> 6);
  const int lane = t & 63;
  const int s = src[e], d = dst[e];
  const float* hp = HP   + (size_t)s*256;
  const float* hc = hcat + (size_t)d*256;
  float acc = 0.f;
  for (int k = lane; k < 256; k += 64) acc += hp[k] * hc[k];
  for (int o = 32; o > 0; o >>= 1) acc += __shfl_down(acc, o, 64);
  __shared__ float terms[4];
  if (lane == 0){
    float l = acc + predB[0];
    out[1 + e] = l;
    float y = labels[e];
    terms[t >> 6] = fmaxf(l, 0.f) - l*y + log1pf(expf(-fabsf(l)));
  }
  __syncthreads();
  if (t == 0) partial[blockIdx.x] = terms[0] + terms[1] + terms[2] + terms[3];
}

__global__ __launch_bounds__(256) void reduce_loss(const float* __restrict__ partial,
    float* __restrict__ out){
  const int t = threadIdx.x, lane = t & 63, w = t >> 6;
  float s = 0.f;
  for (int i = t; i < EEDGES/4; i += 256) s += partial[i];
  for (int o = 32; o > 0; o >>= 1) s += __shfl_down(s, o, 64);
  __shared__ float ws[4];
  if (lane == 0) ws[w] = s;
  __syncthreads();
  if (t == 0) out[0] = (ws[0] + ws[1] + ws[2] + ws[3]) * (1.0f / EEDGES);
}

// ---------------------------------------------------------------- launcher
extern "C" void kernel_launch(void* const* d_in, const int* in_sizes, int n_in,
                              void* d_out, int out_size, void* d_ws, size_t ws_size,
                              hipStream_t stream){
  (void)in_sizes; (void)n_in; (void)out_size; (void)ws_size;
  const int*   src    = (const int*)d_in[0];
  const int*   dst    = (const int*)d_in[1];
  const float* labels = (const float*)d_in[2];
  const float* adj    = (const float*)d_in[3];
  const float* x      = (const float*)d_in[4];
  const float* Wg1    = (const float*)d_in[5];
  const float* Wg2    = (const float*)d_in[6];
  const float* Wp1    = (const float*)d_in[7];
  const float* b1     = (const float*)d_in[8];
  const float* Ws1    = (const float*)d_in[9];
  const float* Wp2    = (const float*)d_in[10];
  const float* b2     = (const float*)d_in[11];
  const float* Ws2    = (const float*)d_in[12];
  const float* PredW  = (const float*)d_in[13];
  const float* PredB  = (const float*)d_in[14];

  char* ws = (char*)d_ws;
  size_t off = 0;
  auto alloc = [&](size_t bytes)->void*{
    void* p = ws + off; off += (bytes + 255) & ~(size_t)255; return p; };

  // total ws footprint ~109 MB (ws_size = 576 MiB)
  int*   colcnt = (int*)  alloc((size_t)N_NODES*4);
  int*   nbrcnt = (int*)  alloc((size_t)N_NODES*4);
  int*   nbr    = (int*)  alloc((size_t)N_NODES*MAXNBR*4);
  float* d1inv  = (float*)alloc((size_t)N_NODES*4);
  float* d2inv  = (float*)alloc((size_t)N_NODES*4);
  float* xninv  = (float*)alloc((size_t)N_NODES*4);
  unsigned short* xbf = (unsigned short*)alloc((size_t)N_NODES*FDIM*2);
  float* tval   = (float*)alloc((size_t)N_NODES*KTOP*4);
  int*   tidx   = (int*)  alloc((size_t)N_NODES*KTOP*4);
  float* dginv  = (float*)alloc((size_t)N_NODES*4);
  float* gmax   = (float*)alloc((size_t)N_NODES*NTILES*4);
  float* partial= (float*)alloc((size_t)(EEDGES/4)*4);
  float* T1     = (float*)alloc((size_t)N_NODES*FDIM*4);
  float* T2     = (float*)alloc((size_t)N_NODES*FDIM*4);
  float* z1     = (float*)alloc((size_t)N_NODES*FDIM*4);
  float* cat1   = (float*)alloc((size_t)N_NODES*256*4);
  float* cat2   = (float*)alloc((size_t)N_NODES*256*4);
  float* hcat   = (float*)alloc((size_t)N_NODES*256*4);
  unsigned short* sim = (unsigned short*)alloc((size_t)N_NODES*N_NODES*2);
  float* out    = (float*)d_out;

  hipMemsetAsync(colcnt, 0, (size_t)N_NODES*4, stream);

  prep       <<<N_NODES + N_NODES/2, 256, 0, stream>>>(adj, x, nbr, nbrcnt, colcnt, xbf, xninv, cat1);
  simgemm    <<<dim3(N_NODES/64, GRIDY), 256, 0, stream>>>(xbf, xninv, sim, gmax);
  refine_scan<<<N_NODES, 256, 0, stream>>>(x, xninv, sim, gmax, tval, tidx, dginv);

  // T1 = x@Wg1, T2 = elu(x@Wp1+b1); node_norms folded
  gemm_dual  <<<dim3(N_NODES/32, 2), 256, 0, stream>>>(x, Wg1, Wp1, b1, T1, T2,
                                                       nbrcnt, colcnt, d1inv, d2inv);
  // GCN layer-1 spmm + SAGE layer-1 spmm
  spmm_pair  <<<2*N_NODES, 128, 0, stream>>>(T1, nbr, nbrcnt, d1inv, d2inv, z1,
                                             T2, tval, tidx, dginv, cat1 + 128);
  // T1 = z1@Wg2  ||  cat2[:,0:128] = elu(cat1@Ws1)
  dual_stage1<<<768, 256, 0, stream>>>(z1, Wg2, T1, cat1, Ws1, cat2);
  // hcat[:,0:128] = GCN-L2 spmm(T1)  ||  T2 = elu(cat2@Wp2+b2)
  dual_stage2<<<3072 + 384, 256, 0, stream>>>(T1, nbr, nbrcnt, d1inv, d2inv, hcat,
                                              cat2, Wp2, b2, T2);
  // SAGE layer-2 spmm + combine
  spmm_sage  <<<N_NODES, 128, 0, stream>>>(T2, tval, tidx, dginv, cat2 + 128, 256);
  gemm_k<128><<<dim3(N_NODES/32, 2), 256, 0, stream>>>(cat2, 256, Ws2, nullptr, hcat + 128, 256, 256, 1);

  // predictor
  gemm_k<256><<<dim3(N_NODES/32, 4), 256, 0, stream>>>(hcat, 256, PredW, nullptr, cat1, 256, 256, 0);
  edge_loss  <<<EEDGES/4, 256, 0, stream>>>(src, dst, labels, cat1, hcat, PredB, out, partial);
  reduce_loss<<<1, 256, 0, stream>>>(partial, out);
}